// Round 6
// baseline (88.202 us; speedup 1.0000x reference)
//
#include <hip/hip_runtime.h>
#include <math.h>

#define BATCH    32
#define NHEADS   32
#define KVHEADS  8
#define GRP      4
#define HSZ      128
#define BLKSZ    16
#define BPS      128
#define NTHREADS 512
#define CHUNK    128              // tokens per split (8 cache blocks, dense 512 KB/WG)
#define NSPLIT   16               // 2048 / CHUNK
#define SCALE    0.08838834764831843f

// ws layout (floats): pm[16384] | pl[16384] | po[16384*128]
#define NPART    ((size_t)BATCH * KVHEADS * GRP * NSPLIT)     // 16384
#define WS_FLOATS (NPART * 2 + NPART * HSZ)

// ---------------- split kernel: one WG per (b, chunk); wave w = kvh w ----------------
__global__ __launch_bounds__(NTHREADS, 8) void pa_partial(
    const float* __restrict__ query,
    const float* __restrict__ k_new,
    const float* __restrict__ v_new,
    const float* __restrict__ k_cache,
    const float* __restrict__ v_cache,
    const int*  __restrict__ block_tables,
    const int*  __restrict__ ctx_lens,
    float* __restrict__ pm, float* __restrict__ pl, float* __restrict__ po)
{
    const int chunk = blockIdx.x & (NSPLIT - 1);
    const int b     = blockIdx.x >> 4;
    const int ctx   = ctx_lens[b];
    const int t0    = chunk * CHUNK;
    if (t0 > ctx) return;

    const int tid  = threadIdx.x;
    const int lane = tid & 63;
    const int w    = tid >> 6;          // wave id == kvh

    __shared__ float q_s[KVHEADS][GRP][HSZ];   // 16 KB, roped*SCALE
    __shared__ float kn_s[KVHEADS][HSZ];       // 4 KB, roped k_new
    __shared__ float sp[KVHEADS][CHUNK][GRP];  // 16 KB, scores->probs, wave-private
    __shared__ int   bt_s[CHUNK / BLKSZ];      // 8

    // ---- staging: RoPE(pos=ctx+1) for all 32 q heads + 8 k_new; block table ----
    {
        const int   i    = tid & 63;
        const int   unit = tid >> 6;    // kvh
        const float p    = (float)(ctx + 1);
        const float invf = exp2f(-((float)i / 64.0f) * 13.287712379549449f); // 10000^(-2i/128)
        float s_, c_;
        sincosf(p * invf, &s_, &c_);
#pragma unroll
        for (int g = 0; g < GRP; ++g) {
            const float* qp = query + ((size_t)b * NHEADS + unit * GRP + g) * HSZ;
            const float x1 = qp[i], x2 = qp[i + 64];
            q_s[unit][g][i]      = (x1 * c_ - x2 * s_) * SCALE;
            q_s[unit][g][i + 64] = (x2 * c_ + x1 * s_) * SCALE;
        }
        const float* kp = k_new + ((size_t)b * KVHEADS + unit) * HSZ;
        const float x1 = kp[i], x2 = kp[i + 64];
        kn_s[unit][i]      = x1 * c_ - x2 * s_;
        kn_s[unit][i + 64] = x2 * c_ + x1 * s_;
        if (tid < CHUNK / BLKSZ) bt_s[tid] = block_tables[b * BPS + chunk * (CHUNK / BLKSZ) + tid];
    }
    __syncthreads();

    const int nvalid = min(CHUNK, ctx - t0 + 1);  // valid rows incl. newest
    const bool has_new = (chunk == (ctx >> 7));
    const int tc = ctx - t0;                      // newest row index if has_new

    const int rg = lane >> 2;           // row within 16-token tile
    const int j  = lane & 3;            // dim-slice lane
    const int jo = j << 2;

    // ---- phase 1: scores, 4 lanes/row ----
    if (nvalid == CHUNK) {
        // fast path: all 8 tiles valid; process tiles (tp, tp+4) as dual rows
        for (int tp = 0; tp < 4; ++tp) {
            const float* kb0 = k_cache + (((size_t)bt_s[tp]     * BLKSZ + rg) * KVHEADS + w) * HSZ + jo;
            const float* kb1 = k_cache + (((size_t)bt_s[tp + 4] * BLKSZ + rg) * KVHEADS + w) * HSZ + jo;
            float4 acc0 = make_float4(0.f, 0.f, 0.f, 0.f);
            float4 acc1 = make_float4(0.f, 0.f, 0.f, 0.f);
#pragma unroll
            for (int uu = 0; uu < 2; ++uu) {
                float4 k0[4], k1[4];
#pragma unroll
                for (int u = 0; u < 4; ++u) {
                    k0[u] = *(const float4*)(kb0 + (uu * 4 + u) * 16);
                    k1[u] = *(const float4*)(kb1 + (uu * 4 + u) * 16);
                }
#pragma unroll
                for (int u = 0; u < 4; ++u) {
                    const float* qb = &q_s[w][0][(uu * 4 + u) * 16 + jo];
                    const float4 qa = *(const float4*)(qb);
                    const float4 qg = *(const float4*)(qb + HSZ);
                    const float4 qc = *(const float4*)(qb + 2 * HSZ);
                    const float4 qd = *(const float4*)(qb + 3 * HSZ);
                    acc0.x = fmaf(qa.x,k0[u].x,fmaf(qa.y,k0[u].y,fmaf(qa.z,k0[u].z,fmaf(qa.w,k0[u].w,acc0.x))));
                    acc0.y = fmaf(qg.x,k0[u].x,fmaf(qg.y,k0[u].y,fmaf(qg.z,k0[u].z,fmaf(qg.w,k0[u].w,acc0.y))));
                    acc0.z = fmaf(qc.x,k0[u].x,fmaf(qc.y,k0[u].y,fmaf(qc.z,k0[u].z,fmaf(qc.w,k0[u].w,acc0.z))));
                    acc0.w = fmaf(qd.x,k0[u].x,fmaf(qd.y,k0[u].y,fmaf(qd.z,k0[u].z,fmaf(qd.w,k0[u].w,acc0.w))));
                    acc1.x = fmaf(qa.x,k1[u].x,fmaf(qa.y,k1[u].y,fmaf(qa.z,k1[u].z,fmaf(qa.w,k1[u].w,acc1.x))));
                    acc1.y = fmaf(qg.x,k1[u].x,fmaf(qg.y,k1[u].y,fmaf(qg.z,k1[u].z,fmaf(qg.w,k1[u].w,acc1.y))));
                    acc1.z = fmaf(qc.x,k1[u].x,fmaf(qc.y,k1[u].y,fmaf(qc.z,k1[u].z,fmaf(qc.w,k1[u].w,acc1.z))));
                    acc1.w = fmaf(qd.x,k1[u].x,fmaf(qd.y,k1[u].y,fmaf(qd.z,k1[u].z,fmaf(qd.w,k1[u].w,acc1.w))));
                }
            }
            acc0.x += __shfl_xor(acc0.x,1); acc0.x += __shfl_xor(acc0.x,2);
            acc0.y += __shfl_xor(acc0.y,1); acc0.y += __shfl_xor(acc0.y,2);
            acc0.z += __shfl_xor(acc0.z,1); acc0.z += __shfl_xor(acc0.z,2);
            acc0.w += __shfl_xor(acc0.w,1); acc0.w += __shfl_xor(acc0.w,2);
            acc1.x += __shfl_xor(acc1.x,1); acc1.x += __shfl_xor(acc1.x,2);
            acc1.y += __shfl_xor(acc1.y,1); acc1.y += __shfl_xor(acc1.y,2);
            acc1.z += __shfl_xor(acc1.z,1); acc1.z += __shfl_xor(acc1.z,2);
            acc1.w += __shfl_xor(acc1.w,1); acc1.w += __shfl_xor(acc1.w,2);
            if (j == 0) {
                *(float4*)&sp[w][tp * 16 + rg][0]      = acc0;
                *(float4*)&sp[w][64 + tp * 16 + rg][0] = acc1;
            }
        }
    } else {
        // last-chunk path: single tiles, stop at nvalid
        for (int tile = 0; tile < CHUNK / BLKSZ && tile * 16 < nvalid; ++tile) {
            const float* kb = k_cache + (((size_t)bt_s[tile] * BLKSZ + rg) * KVHEADS + w) * HSZ + jo;
            float4 acc = make_float4(0.f, 0.f, 0.f, 0.f);
#pragma unroll
            for (int u = 0; u < 8; ++u) {
                const float4 kv = *(const float4*)(kb + u * 16);
                const float* qb = &q_s[w][0][u * 16 + jo];
                const float4 qa = *(const float4*)(qb);
                const float4 qg = *(const float4*)(qb + HSZ);
                const float4 qc = *(const float4*)(qb + 2 * HSZ);
                const float4 qd = *(const float4*)(qb + 3 * HSZ);
                acc.x = fmaf(qa.x,kv.x,fmaf(qa.y,kv.y,fmaf(qa.z,kv.z,fmaf(qa.w,kv.w,acc.x))));
                acc.y = fmaf(qg.x,kv.x,fmaf(qg.y,kv.y,fmaf(qg.z,kv.z,fmaf(qg.w,kv.w,acc.y))));
                acc.z = fmaf(qc.x,kv.x,fmaf(qc.y,kv.y,fmaf(qc.z,kv.z,fmaf(qc.w,kv.w,acc.z))));
                acc.w = fmaf(qd.x,kv.x,fmaf(qd.y,kv.y,fmaf(qd.z,kv.z,fmaf(qd.w,kv.w,acc.w))));
            }
            acc.x += __shfl_xor(acc.x,1); acc.x += __shfl_xor(acc.x,2);
            acc.y += __shfl_xor(acc.y,1); acc.y += __shfl_xor(acc.y,2);
            acc.z += __shfl_xor(acc.z,1); acc.z += __shfl_xor(acc.z,2);
            acc.w += __shfl_xor(acc.w,1); acc.w += __shfl_xor(acc.w,2);
            if (j == 0) *(float4*)&sp[w][tile * 16 + rg][0] = acc;
        }
    }
    // newest token: overwrite its score with the roped-k_new dot (LDS only)
    if (has_new && rg == (tc & 15) && (tc >> 4) < CHUNK / BLKSZ) {
        float4 acc = make_float4(0.f, 0.f, 0.f, 0.f);
#pragma unroll
        for (int u = 0; u < 8; ++u) {
            const float4 kv = *(const float4*)&kn_s[w][u * 16 + jo];
            const float* qb = &q_s[w][0][u * 16 + jo];
            const float4 qa = *(const float4*)(qb);
            const float4 qg = *(const float4*)(qb + HSZ);
            const float4 qc = *(const float4*)(qb + 2 * HSZ);
            const float4 qd = *(const float4*)(qb + 3 * HSZ);
            acc.x = fmaf(qa.x,kv.x,fmaf(qa.y,kv.y,fmaf(qa.z,kv.z,fmaf(qa.w,kv.w,acc.x))));
            acc.y = fmaf(qg.x,kv.x,fmaf(qg.y,kv.y,fmaf(qg.z,kv.z,fmaf(qg.w,kv.w,acc.y))));
            acc.z = fmaf(qc.x,kv.x,fmaf(qc.y,kv.y,fmaf(qc.z,kv.z,fmaf(qc.w,kv.w,acc.z))));
            acc.w = fmaf(qd.x,kv.x,fmaf(qd.y,kv.y,fmaf(qd.z,kv.z,fmaf(qd.w,kv.w,acc.w))));
        }
        acc.x += __shfl_xor(acc.x,1); acc.x += __shfl_xor(acc.x,2);
        acc.y += __shfl_xor(acc.y,1); acc.y += __shfl_xor(acc.y,2);
        acc.z += __shfl_xor(acc.z,1); acc.z += __shfl_xor(acc.z,2);
        acc.w += __shfl_xor(acc.w,1); acc.w += __shfl_xor(acc.w,2);
        if (j == 0) *(float4*)&sp[w][tc][0] = acc;
    }

    // ---- phase 2: softmax over 128 tokens, wave-local (2 tokens/lane) ----
    const int tA = lane, tB = lane + 64;
    float4 s0 = *(const float4*)&sp[w][tA][0];
    float4 s1 = *(const float4*)&sp[w][tB][0];
    if (tA >= nvalid) s0 = make_float4(-INFINITY, -INFINITY, -INFINITY, -INFINITY);
    if (tB >= nvalid) s1 = make_float4(-INFINITY, -INFINITY, -INFINITY, -INFINITY);
    float4 mx = make_float4(fmaxf(s0.x, s1.x), fmaxf(s0.y, s1.y),
                            fmaxf(s0.z, s1.z), fmaxf(s0.w, s1.w));
#pragma unroll
    for (int hop = 1; hop <= 32; hop <<= 1) {
        mx.x = fmaxf(mx.x, __shfl_xor(mx.x, hop));
        mx.y = fmaxf(mx.y, __shfl_xor(mx.y, hop));
        mx.z = fmaxf(mx.z, __shfl_xor(mx.z, hop));
        mx.w = fmaxf(mx.w, __shfl_xor(mx.w, hop));
    }
    float4 pr0, pr1;
    pr0.x = __expf(s0.x - mx.x); pr0.y = __expf(s0.y - mx.y);
    pr0.z = __expf(s0.z - mx.z); pr0.w = __expf(s0.w - mx.w);
    pr1.x = __expf(s1.x - mx.x); pr1.y = __expf(s1.y - mx.y);
    pr1.z = __expf(s1.z - mx.z); pr1.w = __expf(s1.w - mx.w);
    *(float4*)&sp[w][tA][0] = pr0;
    *(float4*)&sp[w][tB][0] = pr1;
    float4 ls = make_float4(pr0.x + pr1.x, pr0.y + pr1.y, pr0.z + pr1.z, pr0.w + pr1.w);
#pragma unroll
    for (int hop = 1; hop <= 32; hop <<= 1) {
        ls.x += __shfl_xor(ls.x, hop);
        ls.y += __shfl_xor(ls.y, hop);
        ls.z += __shfl_xor(ls.z, hop);
        ls.w += __shfl_xor(ls.w, hop);
    }
    if (lane == 0) {
        const size_t hd = ((size_t)(b * KVHEADS + w)) * GRP;
        pm[(hd + 0) * NSPLIT + chunk] = mx.x; pl[(hd + 0) * NSPLIT + chunk] = ls.x;
        pm[(hd + 1) * NSPLIT + chunk] = mx.y; pl[(hd + 1) * NSPLIT + chunk] = ls.y;
        pm[(hd + 2) * NSPLIT + chunk] = mx.z; pl[(hd + 2) * NSPLIT + chunk] = ls.z;
        pm[(hd + 3) * NSPLIT + chunk] = mx.w; pl[(hd + 3) * NSPLIT + chunk] = ls.w;
    }

    // ---- phase 3: PV, half-wave per parity, bounded by nvalid ----
    const int hh = lane >> 5;
    const int d0 = (lane & 31) << 2;
    float4 o0 = make_float4(0,0,0,0), o1 = o0, o2 = o0, o3 = o0;
#pragma unroll 4
    for (int t = hh; t < nvalid; t += 2) {
        const int blk = bt_s[t >> 4];
        const float* vb = (has_new && t == tc)
            ? (v_new + ((size_t)b * KVHEADS + w) * HSZ)
            : (v_cache + (((size_t)blk * BLKSZ + (t & 15)) * KVHEADS + w) * HSZ);
        const float4 vv = *(const float4*)(vb + d0);
        const float4 pv = *(const float4*)&sp[w][t][0];
        o0.x += pv.x*vv.x; o0.y += pv.x*vv.y; o0.z += pv.x*vv.z; o0.w += pv.x*vv.w;
        o1.x += pv.y*vv.x; o1.y += pv.y*vv.y; o1.z += pv.y*vv.z; o1.w += pv.y*vv.w;
        o2.x += pv.z*vv.x; o2.y += pv.z*vv.y; o2.z += pv.z*vv.z; o2.w += pv.z*vv.w;
        o3.x += pv.w*vv.x; o3.y += pv.w*vv.y; o3.z += pv.w*vv.z; o3.w += pv.w*vv.w;
    }
    o0.x += __shfl_xor(o0.x,32); o0.y += __shfl_xor(o0.y,32); o0.z += __shfl_xor(o0.z,32); o0.w += __shfl_xor(o0.w,32);
    o1.x += __shfl_xor(o1.x,32); o1.y += __shfl_xor(o1.y,32); o1.z += __shfl_xor(o1.z,32); o1.w += __shfl_xor(o1.w,32);
    o2.x += __shfl_xor(o2.x,32); o2.y += __shfl_xor(o2.y,32); o2.z += __shfl_xor(o2.z,32); o2.w += __shfl_xor(o2.w,32);
    o3.x += __shfl_xor(o3.x,32); o3.y += __shfl_xor(o3.y,32); o3.z += __shfl_xor(o3.z,32); o3.w += __shfl_xor(o3.w,32);
    if (hh == 0) {
        const size_t hd = ((size_t)(b * KVHEADS + w)) * GRP;
        *(float4*)&po[((hd + 0) * NSPLIT + chunk) * HSZ + d0] = o0;
        *(float4*)&po[((hd + 1) * NSPLIT + chunk) * HSZ + d0] = o1;
        *(float4*)&po[((hd + 2) * NSPLIT + chunk) * HSZ + d0] = o2;
        *(float4*)&po[((hd + 3) * NSPLIT + chunk) * HSZ + d0] = o3;
    }
}

// ---------------- reduce kernel: one WG per (b, kvh) ----------------
__global__ __launch_bounds__(NTHREADS) void pa_reduce(
    const int*  __restrict__ ctx_lens,
    const float* __restrict__ pm, const float* __restrict__ pl,
    const float* __restrict__ po, float* __restrict__ out)
{
    const int b    = blockIdx.x >> 3;
    const int kvh  = blockIdx.x & 7;
    const int ctx  = ctx_lens[b];
    const int nact = (ctx >> 7) + 1;
    const int tid  = threadIdx.x;
    const int g    = tid >> 7;
    const int d    = tid & 127;
    const size_t idx = (((size_t)(b * KVHEADS + kvh)) * GRP + g) * NSPLIT;

    float M = -INFINITY;
    for (int p = 0; p < nact; ++p) M = fmaxf(M, pm[idx + p]);
    float L = 0.f, O = 0.f;
    for (int p = 0; p < nact; ++p) {
        const float wgt = __expf(pm[idx + p] - M);
        L += pl[idx + p] * wgt;
        O += po[(idx + p) * HSZ + d] * wgt;
    }
    out[((size_t)b * NHEADS + kvh * GRP + g) * HSZ + d] = O / L;
}

// ---------------- fallback: single kernel (if ws too small) ----------------
__device__ __forceinline__ float hsum32(float v) {
    v += __shfl_xor(v, 1); v += __shfl_xor(v, 2); v += __shfl_xor(v, 4);
    v += __shfl_xor(v, 8); v += __shfl_xor(v, 16);
    return v;
}
__device__ __forceinline__ void proc_row_f(const float4 kv, const float4 vv,
                                           const float4* qf, float* m, float* l, float4* o) {
    float s[GRP];
#pragma unroll
    for (int g = 0; g < GRP; ++g)
        s[g] = qf[g].x*kv.x + qf[g].y*kv.y + qf[g].z*kv.z + qf[g].w*kv.w;
#pragma unroll
    for (int g = 0; g < GRP; ++g) s[g] = hsum32(s[g]);
#pragma unroll
    for (int g = 0; g < GRP; ++g) {
        const float sc = s[g] * SCALE;
        const float mn = fmaxf(m[g], sc);
        const float cf = __expf(m[g] - mn);
        const float pp = __expf(sc - mn);
        l[g] = l[g] * cf + pp;
        o[g].x = o[g].x*cf + pp*vv.x; o[g].y = o[g].y*cf + pp*vv.y;
        o[g].z = o[g].z*cf + pp*vv.z; o[g].w = o[g].w*cf + pp*vv.w;
        m[g] = mn;
    }
}
__global__ __launch_bounds__(NTHREADS) void paged_attn_single(
    const float* __restrict__ query, const float* __restrict__ k_new,
    const float* __restrict__ v_new, const float* __restrict__ k_cache,
    const float* __restrict__ v_cache, const int* __restrict__ block_tables,
    const int* __restrict__ ctx_lens, float* __restrict__ out)
{
    const int wg = blockIdx.x, b = wg >> 3, kvh = wg & 7;
    const int tid = threadIdx.x, sub = tid & 31, proc = tid >> 5;
    const int ctx = ctx_lens[b];
    __shared__ float q_s[GRP][HSZ];
    __shared__ float kn_s[HSZ];
    __shared__ int   bt_s[BPS];
    __shared__ float m_s[16][GRP];
    __shared__ float l_s[16][GRP];
    __shared__ float o_s[16][GRP][HSZ];
    {
        const float p = (float)(ctx + 1);
        if (tid < 320) {
            const int   i    = tid & 63;
            const float invf = exp2f(-((float)i / 64.0f) * 13.287712379549449f);
            float s_, c_;
            sincosf(p * invf, &s_, &c_);
            if (tid < 256) {
                const int g = tid >> 6;
                const float* qp = query + ((size_t)b * NHEADS + kvh * GRP + g) * HSZ;
                const float x1 = qp[i], x2 = qp[i + 64];
                q_s[g][i] = x1*c_ - x2*s_; q_s[g][i+64] = x2*c_ + x1*s_;
            } else {
                const float* kp = k_new + ((size_t)b * KVHEADS + kvh) * HSZ;
                const float x1 = kp[i], x2 = kp[i + 64];
                kn_s[i] = x1*c_ - x2*s_; kn_s[i+64] = x2*c_ + x1*s_;
            }
        } else if (tid < 448) {
            bt_s[tid - 320] = block_tables[b * BPS + (tid - 320)];
        }
    }
    __syncthreads();
    const int d0 = sub << 2;
    float4 qf[GRP];
#pragma unroll
    for (int g = 0; g < GRP; ++g) qf[g] = *(const float4*)&q_s[g][d0];
    float m[GRP], l[GRP]; float4 o[GRP];
#pragma unroll
    for (int g = 0; g < GRP; ++g) { m[g] = -INFINITY; l[g] = 0.f; o[g] = make_float4(0,0,0,0); }
    for (int t = proc; t < ctx; t += 16) {
        const int blk = bt_s[t >> 4];
        const size_t a0 = (((size_t)blk*BLKSZ + (t & 15))*KVHEADS + kvh)*HSZ + d0;
        proc_row_f(*(const float4*)(k_cache + a0), *(const float4*)(v_cache + a0), qf, m, l, o);
    }
    if (proc == (ctx & 15)) {
        proc_row_f(*(const float4*)&kn_s[d0],
                   *(const float4*)(v_new + ((size_t)b*KVHEADS + kvh)*HSZ + d0), qf, m, l, o);
    }
    if (sub == 0) {
#pragma unroll
        for (int g = 0; g < GRP; ++g) { m_s[proc][g] = m[g]; l_s[proc][g] = l[g]; }
    }
#pragma unroll
    for (int g = 0; g < GRP; ++g) *(float4*)&o_s[proc][g][d0] = o[g];
    __syncthreads();
    {
        const int g = tid >> 7, d = tid & 127;
        float mt = -INFINITY;
#pragma unroll
        for (int p = 0; p < 16; ++p) mt = fmaxf(mt, m_s[p][g]);
        float lt = 0.f, ot = 0.f;
#pragma unroll
        for (int p = 0; p < 16; ++p) {
            const float wgt = __expf(m_s[p][g] - mt);
            lt += l_s[p][g]*wgt; ot += o_s[p][g][d]*wgt;
        }
        out[((size_t)b*NHEADS + kvh*GRP + g)*HSZ + d] = ot / lt;
    }
}

extern "C" void kernel_launch(void* const* d_in, const int* in_sizes, int n_in,
                              void* d_out, int out_size, void* d_ws, size_t ws_size,
                              hipStream_t stream) {
    const float* query        = (const float*)d_in[0];
    const float* k_new        = (const float*)d_in[1];
    const float* v_new        = (const float*)d_in[2];
    const float* k_cache      = (const float*)d_in[3];
    const float* v_cache      = (const float*)d_in[4];
    const int*   block_tables = (const int*)d_in[5];
    const int*   ctx_lens     = (const int*)d_in[6];
    float*       out          = (float*)d_out;

    if (ws_size >= WS_FLOATS * sizeof(float)) {
        float* pm = (float*)d_ws;
        float* pl = pm + NPART;
        float* po = pl + NPART;
        pa_partial<<<dim3(BATCH * NSPLIT), dim3(NTHREADS), 0, stream>>>(
            query, k_new, v_new, k_cache, v_cache, block_tables, ctx_lens, pm, pl, po);
        pa_reduce<<<dim3(BATCH * KVHEADS), dim3(NTHREADS), 0, stream>>>(
            ctx_lens, pm, pl, po, out);
    } else {
        paged_attn_single<<<dim3(BATCH * KVHEADS), dim3(NTHREADS), 0, stream>>>(
            query, k_new, v_new, k_cache, v_cache, block_tables, ctx_lens, out);
    }
}

// Round 7
// 72.564 us; speedup vs baseline: 1.2155x; 1.2155x over previous
//
#include <hip/hip_runtime.h>
#include <math.h>

#define BATCH    32
#define NHEADS   32
#define KVHEADS  8
#define GRP      4
#define HSZ      128
#define BLKSZ    16
#define BPS      128
#define NTHREADS 512
#define NPROC    16     // half-wave processors (PV phase)
#define CHUNK    256    // tokens per split
#define NSPLIT   8      // 2048 / CHUNK
#define SCALE    0.08838834764831843f   // 1/sqrt(128)

__device__ __forceinline__ void dot4(float4& acc, const float* qb, const float4 k) {
    const float4 qa = *(const float4*)(qb);
    const float4 qg = *(const float4*)(qb + HSZ);
    const float4 qc = *(const float4*)(qb + 2 * HSZ);
    const float4 qd = *(const float4*)(qb + 3 * HSZ);
    acc.x = fmaf(qa.x,k.x,fmaf(qa.y,k.y,fmaf(qa.z,k.z,fmaf(qa.w,k.w,acc.x))));
    acc.y = fmaf(qg.x,k.x,fmaf(qg.y,k.y,fmaf(qg.z,k.z,fmaf(qg.w,k.w,acc.y))));
    acc.z = fmaf(qc.x,k.x,fmaf(qc.y,k.y,fmaf(qc.z,k.z,fmaf(qc.w,k.w,acc.z))));
    acc.w = fmaf(qd.x,k.x,fmaf(qd.y,k.y,fmaf(qd.z,k.z,fmaf(qd.w,k.w,acc.w))));
}

__device__ __forceinline__ void red2(float4& a) {
    a.x += __shfl_xor(a.x,1); a.x += __shfl_xor(a.x,2);
    a.y += __shfl_xor(a.y,1); a.y += __shfl_xor(a.y,2);
    a.z += __shfl_xor(a.z,1); a.z += __shfl_xor(a.z,2);
    a.w += __shfl_xor(a.w,1); a.w += __shfl_xor(a.w,2);
}

__device__ __forceinline__ void pvfma(float4* o, const float4 pv, const float4 vv) {
    o[0].x += pv.x*vv.x; o[0].y += pv.x*vv.y; o[0].z += pv.x*vv.z; o[0].w += pv.x*vv.w;
    o[1].x += pv.y*vv.x; o[1].y += pv.y*vv.y; o[1].z += pv.y*vv.z; o[1].w += pv.y*vv.w;
    o[2].x += pv.z*vv.x; o[2].y += pv.z*vv.y; o[2].z += pv.z*vv.z; o[2].w += pv.z*vv.w;
    o[3].x += pv.w*vv.x; o[3].y += pv.w*vv.y; o[3].z += pv.w*vv.z; o[3].w += pv.w*vv.w;
}

// ---------------- split kernel: one WG per (b, kvh, chunk) ----------------
__global__ __launch_bounds__(NTHREADS, 8) void pa_partial(
    const float* __restrict__ query,
    const float* __restrict__ k_new,
    const float* __restrict__ v_new,
    const float* __restrict__ k_cache,
    const float* __restrict__ v_cache,
    const int*  __restrict__ block_tables,
    const int*  __restrict__ ctx_lens,
    float* __restrict__ pm, float* __restrict__ pl, float* __restrict__ po)
{
    const int wg    = blockIdx.x;
    const int chunk = wg & (NSPLIT - 1);
    const int kvh   = (wg >> 3) & (KVHEADS - 1);
    const int b     = wg >> 6;
    const int ctx   = ctx_lens[b];
    const int t0    = chunk * CHUNK;
    if (t0 > ctx) return;

    const int tid  = threadIdx.x;
    const int lane = tid & 63;
    const int wave = tid >> 6;

    __shared__ float q_s[GRP][HSZ];       // pre-scaled by SCALE
    __shared__ float kn_s[HSZ];
    __shared__ int   bt_s[CHUNK / BLKSZ];
    __shared__ float sp[CHUNK][GRP];      // scores -> probs in place
    __shared__ float redm[8], redl[8];
    __shared__ float o_s[NPROC][GRP][HSZ];

    // ---- init scores to -inf (invalid rows contribute p=0) ----
    {
        float* s1 = &sp[0][0];
        s1[tid]       = -INFINITY;
        s1[tid + 512] = -INFINITY;
    }
    // ---- RoPE (pos = ctx+1) for q heads (pre-scaled) and new k ----
    {
        const float p = (float)(ctx + 1);
        if (tid < 320) {
            const int   i    = tid & 63;
            const float invf = exp2f(-((float)i / 64.0f) * 13.287712379549449f); // 10000^(-2i/128)
            float s_, c_;
            sincosf(p * invf, &s_, &c_);
            if (tid < 256) {
                const int g = tid >> 6;
                const float* qp = query + ((size_t)b * NHEADS + kvh * GRP + g) * HSZ;
                const float x1 = qp[i], x2 = qp[i + 64];
                q_s[g][i]      = (x1 * c_ - x2 * s_) * SCALE;
                q_s[g][i + 64] = (x2 * c_ + x1 * s_) * SCALE;
            } else {
                const float* kp = k_new + ((size_t)b * KVHEADS + kvh) * HSZ;
                const float x1 = kp[i], x2 = kp[i + 64];
                kn_s[i]      = x1 * c_ - x2 * s_;
                kn_s[i + 64] = x2 * c_ + x1 * s_;
            }
        } else if (tid < 320 + CHUNK / BLKSZ) {
            bt_s[tid - 320] = block_tables[b * BPS + (t0 >> 4) + (tid - 320)];
        }
    }
    __syncthreads();

    const int ncache = min(t0 + CHUNK, ctx) - t0;   // rows sourced from cache

    const int rg = lane >> 2;           // row within 16-token tile
    const int j  = lane & 3;            // dim-slice lane
    const int jo = j << 2;

    // ---- phase 1: scores, dual-stream (16 loads in flight per lane) ----
    {
        const int tA0 = wave * 16;
        const int tB0 = 128 + wave * 16;
        if (tB0 < ncache) {
            const float* kra = k_cache + (((size_t)bt_s[tA0 >> 4] * BLKSZ + rg) * KVHEADS + kvh) * HSZ + jo;
            const float* krb = k_cache + (((size_t)bt_s[tB0 >> 4] * BLKSZ + rg) * KVHEADS + kvh) * HSZ + jo;
            float4 ka[8], kb[8];
#pragma unroll
            for (int u = 0; u < 8; ++u) ka[u] = *(const float4*)(kra + u * 16);
#pragma unroll
            for (int u = 0; u < 8; ++u) kb[u] = *(const float4*)(krb + u * 16);
            float4 aA = make_float4(0.f,0.f,0.f,0.f);
            float4 aB = make_float4(0.f,0.f,0.f,0.f);
#pragma unroll
            for (int u = 0; u < 8; ++u) {
                const float* qb = &q_s[0][u * 16 + jo];
                dot4(aA, qb, ka[u]);
                dot4(aB, qb, kb[u]);
            }
            red2(aA); red2(aB);
            if (j == 0) {
                *(float4*)&sp[tA0 + rg][0] = aA;                       // always valid: < 128 <= tB0 < ncache
                if (tB0 + rg < ncache) *(float4*)&sp[tB0 + rg][0] = aB;
            }
        } else if (tA0 < ncache) {
            const float* kra = k_cache + (((size_t)bt_s[tA0 >> 4] * BLKSZ + rg) * KVHEADS + kvh) * HSZ + jo;
            float4 ka[8];
#pragma unroll
            for (int u = 0; u < 8; ++u) ka[u] = *(const float4*)(kra + u * 16);
            float4 aA = make_float4(0.f,0.f,0.f,0.f);
#pragma unroll
            for (int u = 0; u < 8; ++u) dot4(aA, &q_s[0][u * 16 + jo], ka[u]);
            red2(aA);
            if (j == 0 && tA0 + rg < ncache) *(float4*)&sp[tA0 + rg][0] = aA;
        }
    }
    // newest token (t == ctx): score from roped k_new in LDS (wave 0 computes)
    if (chunk == (ctx >> 8) && wave == 0) {
        const int tc = ctx - t0;
        float4 acc = make_float4(0.f,0.f,0.f,0.f);
#pragma unroll
        for (int u = 0; u < 8; ++u) {
            const float4 kv = *(const float4*)&kn_s[u * 16 + jo];
            dot4(acc, &q_s[0][u * 16 + jo], kv);
        }
        red2(acc);
        if (lane == 0) *(float4*)&sp[tc][0] = acc;
    }
    __syncthreads();

    // ---- phase 2: chunk-wide softmax ----
    const int g2 = tid >> 7;
    const int t2 = (tid & 127) << 1;
    const float a0 = sp[t2][g2], a1 = sp[t2 + 1][g2];
    float mx = fmaxf(a0, a1);
    mx = fmaxf(mx, __shfl_xor(mx, 1));
    mx = fmaxf(mx, __shfl_xor(mx, 2));
    mx = fmaxf(mx, __shfl_xor(mx, 4));
    mx = fmaxf(mx, __shfl_xor(mx, 8));
    mx = fmaxf(mx, __shfl_xor(mx, 16));
    mx = fmaxf(mx, __shfl_xor(mx, 32));
    if ((tid & 63) == 0) redm[tid >> 6] = mx;
    __syncthreads();
    const float m_g = fmaxf(redm[g2 << 1], redm[(g2 << 1) + 1]);
    const float p0 = __expf(a0 - m_g);
    const float p1 = __expf(a1 - m_g);
    sp[t2][g2]     = p0;
    sp[t2 + 1][g2] = p1;
    float ls = p0 + p1;
    ls += __shfl_xor(ls, 1);
    ls += __shfl_xor(ls, 2);
    ls += __shfl_xor(ls, 4);
    ls += __shfl_xor(ls, 8);
    ls += __shfl_xor(ls, 16);
    ls += __shfl_xor(ls, 32);
    if ((tid & 63) == 0) redl[tid >> 6] = ls;
    __syncthreads();
    const float l_g = redl[g2 << 1] + redl[(g2 << 1) + 1];

    // ---- phase 3: PV, 2-deep software prefetch, bounded by ncache ----
    const int sub  = tid & 31;
    const int proc = tid >> 5;
    const int d0   = sub << 2;
    float4 o[GRP];
#pragma unroll
    for (int g = 0; g < GRP; ++g) o[g] = make_float4(0.f,0.f,0.f,0.f);
    {
        float4 v0 = make_float4(0.f,0.f,0.f,0.f);
        float4 v1 = v0;
        // branchless valid address helper: clamp to a known-valid row
        #define VADDR(tt, fb) (v_cache + (((size_t)bt_s[(((tt) < ncache) ? (tt) : (fb)) >> 4] * BLKSZ \
                              + ((((tt) < ncache) ? (tt) : (fb)) & 15)) * KVHEADS + kvh) * HSZ + d0)
        if (proc < ncache) {
            v0 = *(const float4*)VADDR(proc, proc);
            v1 = *(const float4*)VADDR(proc + 16, proc);
            for (int t = proc; t < ncache; t += NPROC) {
                const float4 vn = *(const float4*)VADDR(t + 32, t);
                const float4 pv = *(const float4*)&sp[t][0];
                pvfma(o, pv, v0);
                v0 = v1; v1 = vn;
            }
        }
        #undef VADDR
    }
    // newest token: loop above excluded row tc; add p*v_new directly
    if (chunk == (ctx >> 8)) {
        const int tc = ctx - t0;
        if (proc == (tc & (NPROC - 1))) {
            const float4 vn = *(const float4*)(v_new + ((size_t)b * KVHEADS + kvh) * HSZ + d0);
            const float4 pv = *(const float4*)&sp[tc][0];
            pvfma(o, pv, vn);
        }
    }

    // ---- merge 16 procs (pure adds: m,l are chunk-global) ----
#pragma unroll
    for (int g = 0; g < GRP; ++g) *(float4*)&o_s[proc][g][d0] = o[g];
    __syncthreads();
    {
        const int g = tid >> 7;
        const int d = tid & 127;
        float acc = 0.f;
#pragma unroll
        for (int p = 0; p < NPROC; ++p) acc += o_s[p][g][d];
        const size_t idx = (((size_t)(b * KVHEADS + kvh)) * GRP + g) * NSPLIT + chunk;
        if (d == 0) { pm[idx] = m_g; pl[idx] = l_g; }
        po[idx * HSZ + d] = acc;
    }
}

// ---------------- reduce kernel: one WG per (b, kvh) ----------------
__global__ __launch_bounds__(NTHREADS) void pa_reduce(
    const int*  __restrict__ ctx_lens,
    const float* __restrict__ pm, const float* __restrict__ pl,
    const float* __restrict__ po, float* __restrict__ out)
{
    const int b    = blockIdx.x >> 3;
    const int kvh  = blockIdx.x & 7;
    const int ctx  = ctx_lens[b];
    const int nact = (ctx >> 8) + 1;
    const int tid  = threadIdx.x;
    const int g    = tid >> 7;
    const int d    = tid & 127;
    const size_t idx = (((size_t)(b * KVHEADS + kvh)) * GRP + g) * NSPLIT;

    float M = -INFINITY;
    for (int p = 0; p < nact; ++p) M = fmaxf(M, pm[idx + p]);
    float L = 0.f, O = 0.f;
    for (int p = 0; p < nact; ++p) {
        const float w = __expf(pm[idx + p] - M);
        L += pl[idx + p] * w;
        O += po[(idx + p) * HSZ + d] * w;
    }
    out[((size_t)b * NHEADS + kvh * GRP + g) * HSZ + d] = O / L;
}

// ---------------- fallback: single kernel (if ws too small) ----------------
__device__ __forceinline__ float hsum32(float v) {
    v += __shfl_xor(v, 1); v += __shfl_xor(v, 2); v += __shfl_xor(v, 4);
    v += __shfl_xor(v, 8); v += __shfl_xor(v, 16);
    return v;
}
__device__ __forceinline__ void proc_row_f(const float4 kv, const float4 vv,
                                           const float4* qf, float* m, float* l, float4* o) {
    float s[GRP];
#pragma unroll
    for (int g = 0; g < GRP; ++g)
        s[g] = qf[g].x*kv.x + qf[g].y*kv.y + qf[g].z*kv.z + qf[g].w*kv.w;
#pragma unroll
    for (int g = 0; g < GRP; ++g) s[g] = hsum32(s[g]);
#pragma unroll
    for (int g = 0; g < GRP; ++g) {
        const float sc = s[g] * SCALE;
        const float mn = fmaxf(m[g], sc);
        const float cf = __expf(m[g] - mn);
        const float pp = __expf(sc - mn);
        l[g] = l[g] * cf + pp;
        o[g].x = o[g].x*cf + pp*vv.x; o[g].y = o[g].y*cf + pp*vv.y;
        o[g].z = o[g].z*cf + pp*vv.z; o[g].w = o[g].w*cf + pp*vv.w;
        m[g] = mn;
    }
}
__global__ __launch_bounds__(NTHREADS) void paged_attn_single(
    const float* __restrict__ query, const float* __restrict__ k_new,
    const float* __restrict__ v_new, const float* __restrict__ k_cache,
    const float* __restrict__ v_cache, const int* __restrict__ block_tables,
    const int* __restrict__ ctx_lens, float* __restrict__ out)
{
    const int wg = blockIdx.x, b = wg >> 3, kvh = wg & 7;
    const int tid = threadIdx.x, sub = tid & 31, proc = tid >> 5;
    const int ctx = ctx_lens[b];
    __shared__ float q_s[GRP][HSZ];
    __shared__ float kn_s[HSZ];
    __shared__ int   bt_s[BPS];
    __shared__ float m_s[16][GRP];
    __shared__ float l_s[16][GRP];
    __shared__ float o_s[16][GRP][HSZ];
    {
        const float p = (float)(ctx + 1);
        if (tid < 320) {
            const int   i    = tid & 63;
            const float invf = exp2f(-((float)i / 64.0f) * 13.287712379549449f);
            float s_, c_;
            sincosf(p * invf, &s_, &c_);
            if (tid < 256) {
                const int g = tid >> 6;
                const float* qp = query + ((size_t)b * NHEADS + kvh * GRP + g) * HSZ;
                const float x1 = qp[i], x2 = qp[i + 64];
                q_s[g][i] = x1*c_ - x2*s_; q_s[g][i+64] = x2*c_ + x1*s_;
            } else {
                const float* kp = k_new + ((size_t)b * KVHEADS + kvh) * HSZ;
                const float x1 = kp[i], x2 = kp[i + 64];
                kn_s[i] = x1*c_ - x2*s_; kn_s[i+64] = x2*c_ + x1*s_;
            }
        } else if (tid < 448) {
            bt_s[tid - 320] = block_tables[b * BPS + (tid - 320)];
        }
    }
    __syncthreads();
    const int d0 = sub << 2;
    float4 qf[GRP];
#pragma unroll
    for (int g = 0; g < GRP; ++g) qf[g] = *(const float4*)&q_s[g][d0];
    float m[GRP], l[GRP]; float4 o[GRP];
#pragma unroll
    for (int g = 0; g < GRP; ++g) { m[g] = -INFINITY; l[g] = 0.f; o[g] = make_float4(0,0,0,0); }
    for (int t = proc; t < ctx; t += 16) {
        const int blk = bt_s[t >> 4];
        const size_t a0 = (((size_t)blk*BLKSZ + (t & 15))*KVHEADS + kvh)*HSZ + d0;
        proc_row_f(*(const float4*)(k_cache + a0), *(const float4*)(v_cache + a0), qf, m, l, o);
    }
    if (proc == (ctx & 15)) {
        proc_row_f(*(const float4*)&kn_s[d0],
                   *(const float4*)(v_new + ((size_t)b*KVHEADS + kvh)*HSZ + d0), qf, m, l, o);
    }
    if (sub == 0) {
#pragma unroll
        for (int g = 0; g < GRP; ++g) { m_s[proc][g] = m[g]; l_s[proc][g] = l[g]; }
    }
#pragma unroll
    for (int g = 0; g < GRP; ++g) *(float4*)&o_s[proc][g][d0] = o[g];
    __syncthreads();
    {
        const int g = tid >> 7, d = tid & 127;
        float mt = -INFINITY;
#pragma unroll
        for (int p = 0; p < 16; ++p) mt = fmaxf(mt, m_s[p][g]);
        float lt = 0.f, ot = 0.f;
#pragma unroll
        for (int p = 0; p < 16; ++p) {
            const float wgt = __expf(m_s[p][g] - mt);
            lt += l_s[p][g]*wgt; ot += o_s[p][g][d]*wgt;
        }
        out[((size_t)b*NHEADS + kvh*GRP + g)*HSZ + d] = ot / lt;
    }
}

extern "C" void kernel_launch(void* const* d_in, const int* in_sizes, int n_in,
                              void* d_out, int out_size, void* d_ws, size_t ws_size,
                              hipStream_t stream) {
    const float* query        = (const float*)d_in[0];
    const float* k_new        = (const float*)d_in[1];
    const float* v_new        = (const float*)d_in[2];
    const float* k_cache      = (const float*)d_in[3];
    const float* v_cache      = (const float*)d_in[4];
    const int*   block_tables = (const int*)d_in[5];
    const int*   ctx_lens     = (const int*)d_in[6];
    float*       out          = (float*)d_out;

    const size_t NPART = (size_t)BATCH * KVHEADS * GRP * NSPLIT;    // 8192
    const size_t need  = (NPART * 2 + NPART * HSZ) * sizeof(float); // ~4.26 MB

    if (ws_size >= need) {
        float* pm = (float*)d_ws;
        float* pl = pm + NPART;
        float* po = pl + NPART;
        pa_partial<<<dim3(BATCH * KVHEADS * NSPLIT), dim3(NTHREADS), 0, stream>>>(
            query, k_new, v_new, k_cache, v_cache, block_tables, ctx_lens, pm, pl, po);
        pa_reduce<<<dim3(BATCH * KVHEADS), dim3(NTHREADS), 0, stream>>>(
            ctx_lens, pm, pl, po, out);
    } else {
        paged_attn_single<<<dim3(BATCH * KVHEADS), dim3(NTHREADS), 0, stream>>>(
            query, k_new, v_new, k_cache, v_cache, block_tables, ctx_lens, out);
    }
}